// Round 7
// baseline (481.295 us; speedup 1.0000x reference)
//
#include <hip/hip_runtime.h>

// BlockResMLP MixerBlock: 2 layers of 64 independent block MLPs (64->128->64, ELU, residual)
// with a per-row 64x64 transpose (shuffle) around layer 2.  KEY FACT: the whole block is
// row-local -> fully fused. bf16 MFMA (16x16x32 only), fp32 accumulate. 2 kernels:
//   k0: weight convert+transpose. w2t pi32-permuted for ALL layers; w1t pi32 for layer 1.
//   k12_fused: WG = 16 rows x EVERYTHING. Layer-1 (wave: 4 n's, pure-register, verified
//       k1 math) -> zL[n][j][r16] in LDS -> layer-2 (wave: 4 m's, verified k2 register-
//       transpose math, za from LDS, in-place output zL[i][m][r]) -> coalesced fp32 flush.
//       No y1 HBM round trip, one launch for the hot path.

typedef short short8 __attribute__((ext_vector_type(8)));
typedef short short4v __attribute__((ext_vector_type(4)));
typedef float floatx4 __attribute__((ext_vector_type(4)));
typedef unsigned int uintx4 __attribute__((ext_vector_type(4)));

#define MFMA(A, B, C) __builtin_amdgcn_mfma_f32_16x16x32_bf16((A), (B), (C), 0, 0, 0)

__device__ __forceinline__ unsigned short bf16r(float f) {
  unsigned int u = __builtin_bit_cast(unsigned int, f);
  u += 0x7FFFu + ((u >> 16) & 1u);   // round-to-nearest-even
  return (unsigned short)(u >> 16);
}
__device__ __forceinline__ float bf16f(unsigned short h) {
  unsigned int u = ((unsigned int)h) << 16;
  return __builtin_bit_cast(float, u);
}
__device__ __forceinline__ unsigned int pk2(float lo, float hi) {
  return (unsigned int)bf16r(lo) | ((unsigned int)bf16r(hi) << 16);
}
__device__ __forceinline__ float eluf(float v) {
  return v > 0.f ? v : (__expf(v) - 1.f);
}
__device__ __forceinline__ uint4 gather44(const short* A, const short* B, int s) {
  uint4 o;
  o.x = (unsigned int)(unsigned short)A[0 * s] |
        ((unsigned int)(unsigned short)A[1 * s] << 16);
  o.y = (unsigned int)(unsigned short)A[2 * s] |
        ((unsigned int)(unsigned short)A[3 * s] << 16);
  o.z = (unsigned int)(unsigned short)B[0 * s] |
        ((unsigned int)(unsigned short)B[1 * s] << 16);
  o.w = (unsigned int)(unsigned short)B[2 * s] |
        ((unsigned int)(unsigned short)B[3 * s] << 16);
  return o;
}

// ---------------- K0: weight prep (LDS transpose) ---------------- (unchanged, verified)
// w1 fp32 [l][n][d][e] (2,64,64,128)  -> w1t bf16 [l*64+n][e][d-slot]
// w2 fp32 [l][n][e][d'] (2,64,128,64) -> w2t bf16 [l*64+n][d'][e-slot]
// pi32 k-slot permutation within each 32-block:
//   slot c holds k = (c&~31) + ( (c&7)<4 ? 4*((c>>3)&3)+(c&7) : 16+4*((c>>3)&3)+(c&7)-4 )
// Applied to: w1t for ln>=64 (layer-1 GEMM1, transposed-z A-frags);
//             w2t for ALL ln  (both layers' GEMM2 consume register-transposed h).
__global__ __launch_bounds__(256) void k0_prep(const float* __restrict__ w1,
                                               const float* __restrict__ w2,
                                               short* __restrict__ w1t,
                                               short* __restrict__ w2t) {
  __shared__ __align__(16) short T[128 * 72];   // phase A uses [64][136] = 8704 shorts
  const int t  = threadIdx.x;
  const int ln = blockIdx.x >> 1;
  if ((blockIdx.x & 1) == 0) {
    // ---- w1 [64 d][128 e] -> w1t [e][d-slot] ----
    const bool pm = (ln >= 64);
    const float* src = w1 + (size_t)ln * 8192 + t * 32;
    const int d = t >> 2, e0 = (t & 3) * 32;
#pragma unroll
    for (int u = 0; u < 32; u += 2) {
      *(unsigned int*)&T[d * 136 + e0 + u] = pk2(src[u], src[u + 1]);
    }
    __syncthreads();
    const int e = t >> 1, d0 = (t & 1) * 32;
    short* dst = w1t + (size_t)ln * 8192 + e * 64 + d0;
#pragma unroll
    for (int k = 0; k < 4; ++k) {
      const int ta = d0 + (pm ? 4 * k : 8 * k);
      const int tb = d0 + (pm ? 16 + 4 * k : 8 * k + 4);
      *(uint4*)(dst + k * 8) = gather44(&T[ta * 136 + e], &T[tb * 136 + e], 136);
    }
  } else {
    // ---- w2 [128 e][64 d'] -> w2t [d'][e-slot], pi32 for all ln ----
    const float* src = w2 + (size_t)ln * 8192 + t * 32;
    const int e = t >> 1, d0 = (t & 1) * 32;
#pragma unroll
    for (int u = 0; u < 32; u += 2) {
      *(unsigned int*)&T[e * 72 + d0 + u] = pk2(src[u], src[u + 1]);
    }
    __syncthreads();
    const int dp = t >> 2, e0 = (t & 3) * 32;
    short* dst = w2t + (size_t)ln * 8192 + dp * 128 + e0;
#pragma unroll
    for (int k = 0; k < 4; ++k) {
      const int ta = e0 + 4 * k;
      const int tb = e0 + 16 + 4 * k;
      *(uint4*)(dst + k * 8) = gather44(&T[ta * 72 + dp], &T[tb * 72 + dp], 72);
    }
  }
}

// ---------------- K12: fully fused MixerBlock ----------------
// WG = 16 rows (R0..R0+15), 16 waves. zL[n][j][r16]: n-stride NSTR=1048 shorts
// (il-stride lands off-bank -> ~2-way), j-stride 16 shorts, all uint2 ops 8-B aligned.
// Layer-1 output slot [n][j] == layer-2 za input slot; layer-2 output reuses [i][m]
// IN PLACE (column m read fully into registers by its owning wave before overwrite).
#define NSTR 1048
__global__ __launch_bounds__(1024, 4) void k12_fused(
    const float* __restrict__ x,
    const short* __restrict__ w1t, const short* __restrict__ w2t,
    const float* __restrict__ b1,  const float* __restrict__ b2,
    float* __restrict__ out) {
  __shared__ __align__(16) short zL[64 * NSTR];   // 134144 B
  const int tid  = threadIdx.x;
  const int lane = tid & 63;
  const int wv   = tid >> 6;                 // 0..15
  const int il   = lane & 15;
  const int q    = lane >> 4;
  const int R0   = blockIdx.x * 16;

  const floatx4 zero4 = {0.f, 0.f, 0.f, 0.f};
  // 4-slot transpose perm-B: B[k][n] = delta(k == (n>>2)*8 + (n&3)), slots 0..3 of A
  short8 pbH;
#pragma unroll
  for (int v = 0; v < 8; ++v) pbH[v] = (v < 4 && il == q * 4 + v) ? (short)0x3F80 : (short)0;
  // full-slot residual perms: pb0: B[k][n]=d(k==n); pb1: B[k][n]=d(k==n+16)
  short8 pb0, pb1;
#pragma unroll
  for (int v = 0; v < 8; ++v) {
    pb0[v] = (q * 8 + v == il)      ? (short)0x3F80 : (short)0;
    pb1[v] = (q * 8 + v == il + 16) ? (short)0x3F80 : (short)0;
  }

  // ================= layer 1: wave -> n = wv*4+nn =================
  // preload A-frags for all 4 n's (16 independent global loads -> one latency)
  short8 a[4][2];   // [nn][ks]
#pragma unroll
  for (int nn = 0; nn < 4; ++nn) {
#pragma unroll
    for (int ks = 0; ks < 2; ++ks) {
      const float* xp = x + (size_t)(R0 + il) * 4096 + (wv * 4 + nn) * 64 + ks * 32 + q * 8;
      floatx4 f0 = *(const floatx4*)xp;
      floatx4 f1 = *(const floatx4*)(xp + 4);
      short8 t;
#pragma unroll
      for (int u = 0; u < 4; ++u) { t[u] = (short)bf16r(f0[u]); t[4 + u] = (short)bf16r(f1[u]); }
      a[nn][ks] = t;
    }
  }

#pragma unroll
  for (int nn = 0; nn < 4; ++nn) {
    const int n = wv * 4 + nn;
    const short* w1n = w1t + (size_t)n * 8192;
    const short* w2n = w2t + (size_t)n * 8192;
    const float* b1n = b1 + n * 128;
    const float* b2n = b2 + n * 64;

    floatx4 acc2[4] = {};
    for (int hh = 0; hh < 2; ++hh) {
      floatx4 acc1[4] = {};
#pragma unroll
      for (int ks = 0; ks < 2; ++ks)
#pragma unroll
        for (int nt = 0; nt < 4; ++nt) {
          short8 b = *(const short8*)(w1n + (hh * 64 + nt * 16 + il) * 64 + ks * 32 + q * 8);
          acc1[nt] = MFMA(a[nn][ks], b, acc1[nt]);
        }
      // bias + ELU -> bf16 -> h-transpose via perm-B MFMA -> GEMM2 A-frags (pi32 order)
      uintx4 a2w[2];
#pragma unroll
      for (int nt = 0; nt < 4; ++nt) {
        const float bias = b1n[hh * 64 + nt * 16 + il];
        short8 ha = {(short)bf16r(eluf(acc1[nt][0] + bias)),
                     (short)bf16r(eluf(acc1[nt][1] + bias)),
                     (short)bf16r(eluf(acc1[nt][2] + bias)),
                     (short)bf16r(eluf(acc1[nt][3] + bias)),
                     0, 0, 0, 0};
        floatx4 hd = MFMA(ha, pbH, zero4);
        const int ks2l = nt >> 1;
        const int hf   = nt & 1;
        a2w[ks2l][hf * 2 + 0] = pk2(hd[0], hd[1]);
        a2w[ks2l][hf * 2 + 1] = pk2(hd[2], hd[3]);
      }
#pragma unroll
      for (int ks2l = 0; ks2l < 2; ++ks2l) {
        short8 af = __builtin_bit_cast(short8, a2w[ks2l]);
#pragma unroll
        for (int nt2 = 0; nt2 < 4; ++nt2) {
          short8 b = *(const short8*)(w2n + (nt2 * 16 + il) * 128 + hh * 64 + ks2l * 32 + q * 8);
          acc2[nt2] = MFMA(af, b, acc2[nt2]);
        }
      }
    }
    // epilogue: bias + bf16(x) residual from A-frag transpose -> zL[n][j][r16]
#pragma unroll
    for (int ks = 0; ks < 2; ++ks) {
      floatx4 xr[2];
      xr[0] = MFMA(a[nn][ks], pb0, zero4);   // x(row=R0+q*4+rg, d=ks*32+il)
      xr[1] = MFMA(a[nn][ks], pb1, zero4);   // x(row=...,      d=ks*32+16+il)
#pragma unroll
      for (int h = 0; h < 2; ++h) {
        const int nt2 = ks * 2 + h;
        const int j = nt2 * 16 + il;
        const float bias = b2n[j];
        uint2 pk;
        pk.x = pk2(acc2[nt2][0] + bias + xr[h][0],
                   acc2[nt2][1] + bias + xr[h][1]);
        pk.y = pk2(acc2[nt2][2] + bias + xr[h][2],
                   acc2[nt2][3] + bias + xr[h][3]);
        *(uint2*)&zL[n * NSTR + j * 16 + q * 4] = pk;
      }
    }
  }
  __syncthreads();

  // ================= layer 2: wave -> m = wv*4+mm =================
#pragma unroll
  for (int mm = 0; mm < 4; ++mm) {
    const int m = wv * 4 + mm;
    const short* w1m = w1t + (size_t)(64 + m) * 8192;
    const short* w2m = w2t + (size_t)(64 + m) * 8192;
    const float* b1m = b1 + (64 + m) * 128;
    const float* b2m = b2 + (64 + m) * 64;

    // za[nt]: lane (il,q) reg u holds z2(r=q*4+u, d=nt*16+il)   [= residual too]
    short4v za[4];
#pragma unroll
    for (int nt = 0; nt < 4; ++nt)
      za[nt] = *(const short4v*)&zL[(nt * 16 + il) * NSTR + m * 16 + q * 4];

    // z-transpose via perm-B MFMA: zd[nt] lane reg rg = z2(r=il, d=nt*16+q*4+rg)
    floatx4 zd[4];
#pragma unroll
    for (int nt = 0; nt < 4; ++nt) {
      short8 az = {za[nt][0], za[nt][1], za[nt][2], za[nt][3], 0, 0, 0, 0};
      zd[nt] = MFMA(az, pbH, zero4);
    }
    short8 at[2];
#pragma unroll
    for (int ks = 0; ks < 2; ++ks) {
      uintx4 w;
      w[0] = pk2(zd[2 * ks][0], zd[2 * ks][1]);
      w[1] = pk2(zd[2 * ks][2], zd[2 * ks][3]);
      w[2] = pk2(zd[2 * ks + 1][0], zd[2 * ks + 1][1]);
      w[3] = pk2(zd[2 * ks + 1][2], zd[2 * ks + 1][3]);
      at[ks] = __builtin_bit_cast(short8, w);
    }

    floatx4 acc2[4] = {};
    uintx4 a2w[4];
#pragma unroll
    for (int hh = 0; hh < 2; ++hh) {
      floatx4 acc1[4] = {};
#pragma unroll
      for (int ks = 0; ks < 2; ++ks)
#pragma unroll
        for (int nt = 0; nt < 4; ++nt) {
          short8 b = *(const short8*)(w1m + (hh * 64 + nt * 16 + il) * 64 + ks * 32 + q * 8);
          acc1[nt] = MFMA(at[ks], b, acc1[nt]);
        }
#pragma unroll
      for (int nt = 0; nt < 4; ++nt) {
        const float bias = b1m[hh * 64 + nt * 16 + il];
        short8 ha = {(short)bf16r(eluf(acc1[nt][0] + bias)),
                     (short)bf16r(eluf(acc1[nt][1] + bias)),
                     (short)bf16r(eluf(acc1[nt][2] + bias)),
                     (short)bf16r(eluf(acc1[nt][3] + bias)),
                     0, 0, 0, 0};
        floatx4 hd = MFMA(ha, pbH, zero4);
        const int ks2 = hh * 2 + (nt >> 1);
        const int hf  = nt & 1;
        a2w[ks2][hf * 2 + 0] = pk2(hd[0], hd[1]);
        a2w[ks2][hf * 2 + 1] = pk2(hd[2], hd[3]);
      }
    }
#pragma unroll
    for (int ks2 = 0; ks2 < 4; ++ks2) {
      short8 af = __builtin_bit_cast(short8, a2w[ks2]);
#pragma unroll
      for (int nt2 = 0; nt2 < 4; ++nt2) {
        short8 b = *(const short8*)(w2m + (nt2 * 16 + il) * 128 + ks2 * 32 + q * 8);
        acc2[nt2] = MFMA(af, b, acc2[nt2]);
      }
    }
    // epilogue: bias + residual (za regs) -> zL[i][m][r16] IN PLACE
#pragma unroll
    for (int nt2 = 0; nt2 < 4; ++nt2) {
      const int i = nt2 * 16 + il;
      const float bias = b2m[i];
      uint2 pk;
      pk.x = pk2(acc2[nt2][0] + bias + bf16f((unsigned short)za[nt2][0]),
                 acc2[nt2][1] + bias + bf16f((unsigned short)za[nt2][1]));
      pk.y = pk2(acc2[nt2][2] + bias + bf16f((unsigned short)za[nt2][2]),
                 acc2[nt2][3] + bias + bf16f((unsigned short)za[nt2][3]));
      *(uint2*)&zL[i * NSTR + m * 16 + q * 4] = pk;
    }
  }
  __syncthreads();

  // ================= flush: out[R0+r][i*64+m] = zL[i][m][r], fp32, coalesced =================
  const int fm = tid & 63;    // m == lane -> 256-B contiguous stores per instruction
  const int fb = tid >> 6;
#pragma unroll
  for (int k = 0; k < 16; ++k) {
    const int iq = fb * 16 + k;
    const int i  = iq >> 2;
    const int fq = iq & 3;
    uint2 z = *(const uint2*)&zL[i * NSTR + fm * 16 + fq * 4];
    const size_t ob = (size_t)(R0 + fq * 4) * 4096 + i * 64 + fm;
    out[ob]         = bf16f((unsigned short)(z.x & 0xffffu));
    out[ob + 4096]  = bf16f((unsigned short)(z.x >> 16));
    out[ob + 8192]  = bf16f((unsigned short)(z.y & 0xffffu));
    out[ob + 12288] = bf16f((unsigned short)(z.y >> 16));
  }
}

extern "C" void kernel_launch(void* const* d_in, const int* in_sizes, int n_in,
                              void* d_out, int out_size, void* d_ws, size_t ws_size,
                              hipStream_t stream) {
  const float* x  = (const float*)d_in[0];
  const float* w1 = (const float*)d_in[1];
  const float* b1 = (const float*)d_in[2];
  const float* w2 = (const float*)d_in[3];
  const float* b2 = (const float*)d_in[4];
  float* out = (float*)d_out;

  short* w1t = (short*)d_ws;
  short* w2t = w1t + (1u << 20);

  hipLaunchKernelGGL(k0_prep,   dim3(256), dim3(256),  0, stream, w1, w2, w1t, w2t);
  hipLaunchKernelGGL(k12_fused, dim3(512), dim3(1024), 0, stream, x, w1t, w2t, b1, b2, out);
}